// Round 3
// baseline (540.004 us; speedup 1.0000x reference)
//
#include <hip/hip_runtime.h>

// LSTM B=32768, T=512, I=2, H=16 — MFMA recurrence, combined-rcp activations.
// Wave = 16 elements. gates = W_hh(split-bf16) @ h via 2 MFMAs per gate-tile:
//   MFMA1: A1=(W_hi,W_lo interleaved) x B1=(h_hi,h_lo)   -> Whi*hhi + Wlo*hlo
//   MFMA2: A1                         x B2=rot16(B1)     -> Whi*hlo + Wlo*hhi
// C/D layout == next step's B layout, so h never leaves the lane: no LDS /
// cross-lane / barriers in the t-loop.
// Activations: one rcp per (i,f,g) group and one per (o, tanh c) group:
//   c' = [c(1+I)(1+G) + (G-1)(1+F)] / [(1+F)(1+I)(1+G)]
//   h  = (C2-1) / [(1+O)(1+C2)]
// Denominators >= 1 -> no overflow/NaN path; recurrent exp arg clamped +-64.

#define T_STEPS 512
#define LOG2E 1.44269504088896340736f

typedef __bf16 bf16x8 __attribute__((ext_vector_type(8)));
typedef float  f32x4  __attribute__((ext_vector_type(4)));
typedef unsigned int u32x4 __attribute__((ext_vector_type(4)));

union frag_u { u32x4 u; bf16x8 v; };

#if __has_builtin(__builtin_amdgcn_exp2f)
__device__ __forceinline__ float fexp2(float x) { return __builtin_amdgcn_exp2f(x); }
#else
__device__ __forceinline__ float fexp2(float x) { return exp2f(x); }
#endif
#if __has_builtin(__builtin_amdgcn_rcpf)
__device__ __forceinline__ float frcp(float x) { return __builtin_amdgcn_rcpf(x); }
#else
__device__ __forceinline__ float frcp(float x) { return 1.0f / x; }
#endif

// split f32 -> (hi bf16 | lo bf16) by truncation; low16 = hi, high16 = lo.
__device__ __forceinline__ unsigned pack_hilo(float h) {
    unsigned hb = __float_as_uint(h);
    float    res = h - __uint_as_float(hb & 0xFFFF0000u);
#if __has_builtin(__builtin_amdgcn_perm)
    return __builtin_amdgcn_perm(__float_as_uint(res), hb, 0x07060302u);
#else
    return (hb >> 16) | (__float_as_uint(res) & 0xFFFF0000u);
#endif
}
__device__ __forceinline__ unsigned rot16(unsigned w) {
    return (w >> 16) | (w << 16);   // compiler emits v_alignbit_b32
}

__global__ __launch_bounds__(256, 2)
void lstm_mfma_kernel(const float* __restrict__ x,
                      const float* __restrict__ W_ih,
                      const float* __restrict__ W_hh,
                      const float* __restrict__ b_ih,
                      const float* __restrict__ b_hh,
                      const float* __restrict__ W1,
                      const float* __restrict__ b1,
                      const float* __restrict__ W2,
                      const float* __restrict__ b2,
                      float* __restrict__ out)
{
    __shared__ float hsm[4][16][16];   // head only; per-wave private, no barriers

    const int tid  = threadIdx.x;
    const int wv   = tid >> 6;
    const int lane = tid & 63;
    const int e    = lane & 15;        // elem within wave (C/D col, B col)
    const int q    = lane >> 4;        // quad (C/D row block, B k-block)

    // static A fragments: W_hh gate tiles, (hi,lo) k-interleaved split-bf16.
    // A[m][k]: m = lane&15 -> gate row 16t+m; k = q*8+j -> unit 4q+(j>>1), part j&1.
    frag_u A1[4];
    #pragma unroll
    for (int t = 0; t < 4; ++t) {
        const int row = 16 * t + (lane & 15);
        const float4 w4 = *(const float4*)(W_hh + row * 16 + 4 * q);
        A1[t].u[0] = pack_hilo(w4.x);
        A1[t].u[1] = pack_hilo(w4.y);
        A1[t].u[2] = pack_hilo(w4.z);
        A1[t].u[3] = pack_hilo(w4.w);
    }

    // x-proj weights + combined bias for the gate rows this lane's acc holds:
    // C/D: lane holds tile-local rows m = 4q + r -> global rows 16t + 4q + r.
    float wxw[4][4], wyw[4][4], bsw[4][4];
    #pragma unroll
    for (int t = 0; t < 4; ++t)
        #pragma unroll
        for (int r = 0; r < 4; ++r) {
            const int row = 16 * t + 4 * q + r;
            wxw[t][r] = W_ih[row * 2 + 0];
            wyw[t][r] = W_ih[row * 2 + 1];
            bsw[t][r] = b_ih[row] + b_hh[row];
        }

    const int gelem = blockIdx.x * 64 + wv * 16 + e;
    const float4* xp = (const float4*)(x + (size_t)gelem * (T_STEPS * 2));

    frag_u B1, B2;                     // h_{t-1}: (hi,lo) and (lo,hi) packs
    #pragma unroll
    for (int w = 0; w < 4; ++w) { B1.u[w] = 0u; B2.u[w] = 0u; }
    float c[4] = {0.f, 0.f, 0.f, 0.f};

    float4 xv = xp[0];

    for (int t2 = 0; t2 < T_STEPS / 2; ++t2) {
        const float4 xnext = xp[(t2 + 1) & (T_STEPS / 2 - 1)];

        #pragma unroll
        for (int half = 0; half < 2; ++half) {
            const float xa = half ? xv.z : xv.x;
            const float xb = half ? xv.w : xv.y;

            f32x4 acc[4];
            #pragma unroll
            for (int t = 0; t < 4; ++t) {
                f32x4 ini;
                #pragma unroll
                for (int r = 0; r < 4; ++r)
                    ini[r] = fmaf(wxw[t][r], xa, fmaf(wyw[t][r], xb, bsw[t][r]));
                acc[t] = __builtin_amdgcn_mfma_f32_16x16x32_bf16(A1[t].v, B1.v, ini, 0, 0, 0);
                acc[t] = __builtin_amdgcn_mfma_f32_16x16x32_bf16(A1[t].v, B2.v, acc[t], 0, 0, 0);
            }

            #pragma unroll
            for (int r = 0; r < 4; ++r) {
                const float ai = acc[0][r], af = acc[1][r];
                const float ag = acc[2][r], ao = acc[3][r];

                // c' = sigma(af)*c + sigma(ai)*tanh(ag), one rcp:
                const float I = fexp2(ai * -LOG2E);
                const float F = fexp2(af * -LOG2E);
                const float G = fexp2(ag * (2.0f * LOG2E));
                const float u  = (1.0f + I) * (1.0f + G);
                const float vf = 1.0f + F;
                const float R1 = frcp(u * vf);
                const float cn = fmaf(c[r], u, (G - 1.0f) * vf) * R1;
                c[r] = cn;

                // h = sigma(ao)*tanh(c'), one rcp:
                const float O = fexp2(ao * -LOG2E);
                float arg = cn * (2.0f * LOG2E);
                arg = fminf(fmaxf(arg, -64.0f), 64.0f);   // inline consts
                const float C2 = fexp2(arg);
                const float R2 = frcp((1.0f + O) * (1.0f + C2));
                const float hn = (C2 - 1.0f) * R2;

                B1.u[r] = pack_hilo(hn);
                B2.u[r] = rot16(B1.u[r]);
            }
        }
        xv = xnext;
    }

    // ---- MLP head: z = tanh(W1 h + b1); y = W2 z + b2. Intra-wave, no barrier.
    #pragma unroll
    for (int r = 0; r < 4; ++r) {
        const unsigned w = B1.u[r];
        const float hval = __uint_as_float(w << 16) +          // hi part
                           __uint_as_float(w & 0xFFFF0000u);   // lo part
        hsm[wv][e][4 * q + r] = hval;
    }

    float hv[16];
    #pragma unroll
    for (int j = 0; j < 4; ++j) {
        const float4 t4 = *(const float4*)&hsm[wv][e][4 * j];
        hv[4 * j + 0] = t4.x; hv[4 * j + 1] = t4.y;
        hv[4 * j + 2] = t4.z; hv[4 * j + 3] = t4.w;
    }

    float z[4];
    #pragma unroll
    for (int r = 0; r < 4; ++r) {
        const int m = 4 * q + r;
        float a = b1[m];
        #pragma unroll
        for (int j = 0; j < 16; ++j) a = fmaf(W1[m * 16 + j], hv[j], a);
        // tanh via the same one-rcp form
        float targ = a * (2.0f * LOG2E);
        targ = fminf(fmaxf(targ, -64.0f), 64.0f);
        const float E = fexp2(targ);
        z[r] = (E - 1.0f) * frcp(1.0f + E);
    }
    #pragma unroll
    for (int r = 0; r < 4; ++r) hsm[wv][e][4 * q + r] = z[r];

    if (q < 2) {
        float a = b2[q];
        #pragma unroll
        for (int j = 0; j < 16; ++j) a = fmaf(W2[q * 16 + j], hsm[wv][e][j], a);
        out[(size_t)gelem * 2 + q] = a;
    }
}

extern "C" void kernel_launch(void* const* d_in, const int* in_sizes, int n_in,
                              void* d_out, int out_size, void* d_ws, size_t ws_size,
                              hipStream_t stream) {
    const float* x    = (const float*)d_in[0];
    const float* W_ih = (const float*)d_in[1];
    const float* W_hh = (const float*)d_in[2];
    const float* b_ih = (const float*)d_in[3];
    const float* b_hh = (const float*)d_in[4];
    const float* W1   = (const float*)d_in[5];
    const float* b1   = (const float*)d_in[6];
    const float* W2   = (const float*)d_in[7];
    const float* b2   = (const float*)d_in[8];
    float* out = (float*)d_out;

    // 32768 elems / 64 per block (4 waves x 16) = 512 blocks
    lstm_mfma_kernel<<<dim3(512), dim3(256), 0, stream>>>(
        x, W_ih, W_hh, b_ih, b_hh, W1, b1, W2, b2, out);
}

// Round 4
// 516.241 us; speedup vs baseline: 1.0460x; 1.0460x over previous
//
#include <hip/hip_runtime.h>

// LSTM B=32768, T=512, I=2, H=16 — MFMA recurrence (r2 structure) +
// exp2-scale folding. Tile t == gate t, so the per-gate exp2 argument scales
// (i,f,o: -log2e; g: +2log2e) are folded into W_hh/W_ih/bias at setup: gates
// exit the MFMA ready for exp2 (no arg muls). c is kept in the 2log2e-scaled
// domain so tanh(c) also consumes it directly.
// Wave = 16 elems; A1=(Whi,Wlo) interleaved, A2=(Wlo,Whi); both MFMAs use the
// same B=(hhi,hlo) pack -> exact split product, one pack per h.
// C/D layout == next B layout: no LDS / cross-lane / barriers in the t-loop.

#define T_STEPS 512
#define LOG2E 1.44269504088896340736f

typedef __bf16 bf16x8 __attribute__((ext_vector_type(8)));
typedef float  f32x4  __attribute__((ext_vector_type(4)));
typedef unsigned int u32x4 __attribute__((ext_vector_type(4)));

union frag_u { u32x4 u; bf16x8 v; };

#if __has_builtin(__builtin_amdgcn_exp2f)
__device__ __forceinline__ float fexp2(float x) { return __builtin_amdgcn_exp2f(x); }
#else
__device__ __forceinline__ float fexp2(float x) { return exp2f(x); }
#endif
#if __has_builtin(__builtin_amdgcn_rcpf)
__device__ __forceinline__ float frcp(float x) { return __builtin_amdgcn_rcpf(x); }
#else
__device__ __forceinline__ float frcp(float x) { return 1.0f / x; }
#endif

// split f32 -> (hi bf16 | lo bf16) by truncation; low16 = hi, high16 = lo.
__device__ __forceinline__ unsigned pack_hilo(float h) {
    unsigned hb = __float_as_uint(h);
    float    res = h - __uint_as_float(hb & 0xFFFF0000u);
#if __has_builtin(__builtin_amdgcn_perm)
    return __builtin_amdgcn_perm(__float_as_uint(res), hb, 0x07060302u);
#else
    return (hb >> 16) | (__float_as_uint(res) & 0xFFFF0000u);
#endif
}
__device__ __forceinline__ unsigned pack_lohi(float h) {
    unsigned hb = __float_as_uint(h);
    float    res = h - __uint_as_float(hb & 0xFFFF0000u);
#if __has_builtin(__builtin_amdgcn_perm)
    return __builtin_amdgcn_perm(__float_as_uint(res), hb, 0x03020706u);
#else
    return (__float_as_uint(res) >> 16) | (hb & 0xFFFF0000u);
#endif
}

__global__ __launch_bounds__(256, 2)
void lstm_mfma_kernel(const float* __restrict__ x,
                      const float* __restrict__ W_ih,
                      const float* __restrict__ W_hh,
                      const float* __restrict__ b_ih,
                      const float* __restrict__ b_hh,
                      const float* __restrict__ W1,
                      const float* __restrict__ b1,
                      const float* __restrict__ W2,
                      const float* __restrict__ b2,
                      float* __restrict__ out)
{
    __shared__ float hsm[4][16][16];   // head only; per-wave private, no barriers

    const int tid  = threadIdx.x;
    const int wv   = tid >> 6;
    const int lane = tid & 63;
    const int e    = lane & 15;        // elem within wave (C/D col, B col)
    const int q    = lane >> 4;        // quad (C/D row block, B k-block)

    // per-gate exp2-argument scales, folded into all gate-row weights/biases
    const float gsc[4] = { -LOG2E, -LOG2E, 2.0f * LOG2E, -LOG2E };

    // static A fragments: s_t * W_hh gate tiles, split-bf16, 2 k-interleave packs.
    // A[m][k]: m = lane&15 -> gate row 16t+m; k = q*8+j -> unit 4q+(j>>1), part j&1.
    frag_u A1[4], A2[4];
    #pragma unroll
    for (int t = 0; t < 4; ++t) {
        const int row = 16 * t + (lane & 15);
        const float4 w4 = *(const float4*)(W_hh + row * 16 + 4 * q);
        const float wa[4] = {w4.x * gsc[t], w4.y * gsc[t], w4.z * gsc[t], w4.w * gsc[t]};
        #pragma unroll
        for (int w = 0; w < 4; ++w) {
            A1[t].u[w] = pack_hilo(wa[w]);
            A2[t].u[w] = pack_lohi(wa[w]);
        }
    }

    // x-proj weights + combined bias (scaled) for the gate rows this lane holds:
    // C/D: lane holds tile-local rows m = 4q + r -> global rows 16t + 4q + r.
    float wxw[4][4], wyw[4][4], bsw[4][4];
    #pragma unroll
    for (int t = 0; t < 4; ++t)
        #pragma unroll
        for (int r = 0; r < 4; ++r) {
            const int row = 16 * t + 4 * q + r;
            wxw[t][r] = W_ih[row * 2 + 0] * gsc[t];
            wyw[t][r] = W_ih[row * 2 + 1] * gsc[t];
            bsw[t][r] = (b_ih[row] + b_hh[row]) * gsc[t];
        }

    const int gelem = blockIdx.x * 64 + wv * 16 + e;
    const float4* xp = (const float4*)(x + (size_t)gelem * (T_STEPS * 2));

    frag_u B;                          // h_{t-1} as B operand (split-bf16, interleaved)
    B.u[0] = 0u; B.u[1] = 0u; B.u[2] = 0u; B.u[3] = 0u;
    float cs[4] = {0.f, 0.f, 0.f, 0.f};   // c in 2log2e-scaled domain
    float h[4]  = {0.f, 0.f, 0.f, 0.f};

    float4 xv = xp[0];

    for (int t2 = 0; t2 < T_STEPS / 2; ++t2) {
        const float4 xnext = xp[(t2 + 1) & (T_STEPS / 2 - 1)];

        #pragma unroll
        for (int half = 0; half < 2; ++half) {
            const float xa = half ? xv.z : xv.x;
            const float xb = half ? xv.w : xv.y;

            f32x4 acc[4];
            #pragma unroll
            for (int t = 0; t < 4; ++t) {
                f32x4 ini;
                #pragma unroll
                for (int r = 0; r < 4; ++r)
                    ini[r] = fmaf(wxw[t][r], xa, fmaf(wyw[t][r], xb, bsw[t][r]));
                acc[t] = __builtin_amdgcn_mfma_f32_16x16x32_bf16(A1[t].v, B.v, ini, 0, 0, 0);
                acc[t] = __builtin_amdgcn_mfma_f32_16x16x32_bf16(A2[t].v, B.v, acc[t], 0, 0, 0);
            }

            // acc[t][r] is already exp2-ready (pre-scaled):
            //   sigmoid(g) = rcp(1 + exp2(-L*g)); tanh(g) = 1 - 2*rcp(1 + exp2(2L*g))
            #pragma unroll
            for (int r = 0; r < 4; ++r) {
                const float si = frcp(1.0f + fexp2(acc[0][r]));
                const float sf = frcp(1.0f + fexp2(acc[1][r]));
                const float tg = fmaf(-2.0f, frcp(1.0f + fexp2(acc[2][r])), 1.0f);
                const float so = frcp(1.0f + fexp2(acc[3][r]));

                // Cs = 2L*c ; Cs' = sf*Cs + (si*tg)*2L  (scale off the critical path)
                cs[r] = fmaf(sf, cs[r], (si * tg) * (2.0f * LOG2E));
                const float tc = fmaf(-2.0f, frcp(1.0f + fexp2(cs[r])), 1.0f);
                const float hn = so * tc;
                h[r] = hn;
                B.u[r] = pack_hilo(hn);   // == next step's B operand word r
            }
        }
        xv = xnext;
    }

    // ---- MLP head: z = tanh(W1 h + b1); y = W2 z + b2. Intra-wave, no barrier.
    #pragma unroll
    for (int r = 0; r < 4; ++r) hsm[wv][e][4 * q + r] = h[r];

    float hv[16];
    #pragma unroll
    for (int j = 0; j < 4; ++j) {
        const float4 t4 = *(const float4*)&hsm[wv][e][4 * j];
        hv[4 * j + 0] = t4.x; hv[4 * j + 1] = t4.y;
        hv[4 * j + 2] = t4.z; hv[4 * j + 3] = t4.w;
    }

    float z[4];
    #pragma unroll
    for (int r = 0; r < 4; ++r) {
        const int m = 4 * q + r;
        float a = b1[m];
        #pragma unroll
        for (int j = 0; j < 16; ++j) a = fmaf(W1[m * 16 + j], hv[j], a);
        const float E = fexp2(a * (2.0f * LOG2E));
        z[r] = fmaf(-2.0f, frcp(1.0f + E), 1.0f);   // safe at +-inf
    }
    #pragma unroll
    for (int r = 0; r < 4; ++r) hsm[wv][e][4 * q + r] = z[r];

    if (q < 2) {
        float a = b2[q];
        #pragma unroll
        for (int j = 0; j < 16; ++j) a = fmaf(W2[q * 16 + j], hsm[wv][e][j], a);
        out[(size_t)gelem * 2 + q] = a;
    }
}

extern "C" void kernel_launch(void* const* d_in, const int* in_sizes, int n_in,
                              void* d_out, int out_size, void* d_ws, size_t ws_size,
                              hipStream_t stream) {
    const float* x    = (const float*)d_in[0];
    const float* W_ih = (const float*)d_in[1];
    const float* W_hh = (const float*)d_in[2];
    const float* b_ih = (const float*)d_in[3];
    const float* b_hh = (const float*)d_in[4];
    const float* W1   = (const float*)d_in[5];
    const float* b1   = (const float*)d_in[6];
    const float* W2   = (const float*)d_in[7];
    const float* b2   = (const float*)d_in[8];
    float* out = (float*)d_out;

    // 32768 elems / 64 per block (4 waves x 16) = 512 blocks
    lstm_mfma_kernel<<<dim3(512), dim3(256), 0, stream>>>(
        x, W_ih, W_hh, b_ih, b_hh, W1, b1, W2, b2, out);
}

// Round 5
// 489.152 us; speedup vs baseline: 1.1040x; 1.0554x over previous
//
#include <hip/hip_runtime.h>

// LSTM B=32768, T=512, I=2, H=16 — MFMA recurrence + pair-fused activations
// + packed-FP32 (f32x2) activation arithmetic.
// Wave = 16 elems. gates exit 2 chained MFMAs (A1=(Whi,Wlo), A2=(Wlo,Whi),
// same B=(h_hi,h_lo)) pre-scaled for exp2 (per-gate scale folded into W/b).
// Activations (per r, all chains parallel, 8 trans instead of 10):
//   2L*si*tg = 2L(G-1) / [(1+I)(1+G)]          (one rcp)
//   sf = (1+O)*R2, so = (1+F)*R2, R2 = rcp((1+F)(1+O))   (one rcp)
//   cs' = sf*cs + 2L*si*tg        (cs = 2L*c domain)
//   tanh(c) = 1 - 2*rcp(1+exp2(cs'))   (inf-safe), h = so*tanh(c)
// r-pairs {0,1},{2,3} run in f32x2 -> v_pk_* on gfx950.
// C/D layout == next B layout: no LDS/cross-lane/barriers in the t-loop.

#define T_STEPS 512
#define LOG2E 1.44269504088896340736f

typedef __bf16 bf16x8 __attribute__((ext_vector_type(8)));
typedef float  f32x4  __attribute__((ext_vector_type(4)));
typedef float  f32x2  __attribute__((ext_vector_type(2)));
typedef unsigned int u32x4 __attribute__((ext_vector_type(4)));

union frag_u { u32x4 u; bf16x8 v; };

#if __has_builtin(__builtin_amdgcn_exp2f)
__device__ __forceinline__ float fexp2(float x) { return __builtin_amdgcn_exp2f(x); }
#else
__device__ __forceinline__ float fexp2(float x) { return exp2f(x); }
#endif
#if __has_builtin(__builtin_amdgcn_rcpf)
__device__ __forceinline__ float frcp(float x) { return __builtin_amdgcn_rcpf(x); }
#else
__device__ __forceinline__ float frcp(float x) { return 1.0f / x; }
#endif

__device__ __forceinline__ f32x2 vexp2(f32x2 a) { f32x2 r; r.x = fexp2(a.x); r.y = fexp2(a.y); return r; }
__device__ __forceinline__ f32x2 vrcp (f32x2 a) { f32x2 r; r.x = frcp(a.x);  r.y = frcp(a.y);  return r; }

// split f32 -> (hi bf16 | lo bf16) by truncation; low16 = hi, high16 = lo.
__device__ __forceinline__ unsigned pack_hilo(float h) {
    unsigned hb = __float_as_uint(h);
    float    res = h - __uint_as_float(hb & 0xFFFF0000u);
#if __has_builtin(__builtin_amdgcn_perm)
    return __builtin_amdgcn_perm(__float_as_uint(res), hb, 0x07060302u);
#else
    return (hb >> 16) | (__float_as_uint(res) & 0xFFFF0000u);
#endif
}
__device__ __forceinline__ unsigned pack_lohi(float h) {
    unsigned hb = __float_as_uint(h);
    float    res = h - __uint_as_float(hb & 0xFFFF0000u);
#if __has_builtin(__builtin_amdgcn_perm)
    return __builtin_amdgcn_perm(__float_as_uint(res), hb, 0x03020706u);
#else
    return (__float_as_uint(res) >> 16) | (hb & 0xFFFF0000u);
#endif
}

__global__ __launch_bounds__(256, 2)
void lstm_mfma_kernel(const float* __restrict__ x,
                      const float* __restrict__ W_ih,
                      const float* __restrict__ W_hh,
                      const float* __restrict__ b_ih,
                      const float* __restrict__ b_hh,
                      const float* __restrict__ W1,
                      const float* __restrict__ b1,
                      const float* __restrict__ W2,
                      const float* __restrict__ b2,
                      float* __restrict__ out)
{
    __shared__ float hsm[4][16][16];   // head only; per-wave private, no barriers

    const int tid  = threadIdx.x;
    const int wv   = tid >> 6;
    const int lane = tid & 63;
    const int e    = lane & 15;        // elem within wave (C/D col, B col)
    const int q    = lane >> 4;        // quad (C/D row block, B k-block)

    // per-gate exp2-argument scales, folded into all gate-row weights/biases
    const float gsc[4] = { -LOG2E, -LOG2E, 2.0f * LOG2E, -LOG2E };

    // static A fragments: s_t * W_hh gate tiles, split-bf16, 2 k-interleave packs.
    frag_u A1[4], A2[4];
    #pragma unroll
    for (int t = 0; t < 4; ++t) {
        const int row = 16 * t + (lane & 15);
        const float4 w4 = *(const float4*)(W_hh + row * 16 + 4 * q);
        const float wa[4] = {w4.x * gsc[t], w4.y * gsc[t], w4.z * gsc[t], w4.w * gsc[t]};
        #pragma unroll
        for (int w = 0; w < 4; ++w) {
            A1[t].u[w] = pack_hilo(wa[w]);
            A2[t].u[w] = pack_lohi(wa[w]);
        }
    }

    // x-proj weights + combined bias (scaled), as f32x2 pairs over r:
    // lane holds tile-local rows m = 4q + {2p, 2p+1} -> global rows 16t+4q+...
    f32x2 wx2[4][2], wy2[4][2], bs2[4][2];
    #pragma unroll
    for (int t = 0; t < 4; ++t)
        #pragma unroll
        for (int p = 0; p < 2; ++p) {
            const int r0 = 16 * t + 4 * q + 2 * p;
            const int r1 = r0 + 1;
            wx2[t][p].x = W_ih[r0 * 2 + 0] * gsc[t];
            wx2[t][p].y = W_ih[r1 * 2 + 0] * gsc[t];
            wy2[t][p].x = W_ih[r0 * 2 + 1] * gsc[t];
            wy2[t][p].y = W_ih[r1 * 2 + 1] * gsc[t];
            bs2[t][p].x = (b_ih[r0] + b_hh[r0]) * gsc[t];
            bs2[t][p].y = (b_ih[r1] + b_hh[r1]) * gsc[t];
        }

    const int gelem = blockIdx.x * 64 + wv * 16 + e;
    const float4* xp = (const float4*)(x + (size_t)gelem * (T_STEPS * 2));

    frag_u B;                              // h_{t-1} (split-bf16, k-interleaved)
    B.u[0] = 0u; B.u[1] = 0u; B.u[2] = 0u; B.u[3] = 0u;
    f32x2 cs2[2];                          // c in 2log2e-scaled domain, r-paired
    cs2[0] = 0.0f; cs2[1] = 0.0f;

    float4 xv = xp[0];

    for (int t2 = 0; t2 < T_STEPS / 2; ++t2) {
        const float4 xnext = xp[(t2 + 1) & (T_STEPS / 2 - 1)];

        // ---- x-projection for BOTH halves (depends only on x: independent
        // work the scheduler can slot into trans/MFMA wait gaps)
        f32x4 ini[2][4];
        #pragma unroll
        for (int half = 0; half < 2; ++half) {
            const float xa = half ? xv.z : xv.x;
            const float xb = half ? xv.w : xv.y;
            #pragma unroll
            for (int t = 0; t < 4; ++t)
                #pragma unroll
                for (int p = 0; p < 2; ++p) {
                    f32x2 v = wy2[t][p] * xb + bs2[t][p];   // v_pk_fma_f32
                    v = wx2[t][p] * xa + v;
                    ini[half][t][2 * p]     = v.x;
                    ini[half][t][2 * p + 1] = v.y;
                }
        }

        #pragma unroll
        for (int half = 0; half < 2; ++half) {
            f32x4 acc[4];
            #pragma unroll
            for (int t = 0; t < 4; ++t) {
                acc[t] = __builtin_amdgcn_mfma_f32_16x16x32_bf16(A1[t].v, B.v, ini[half][t], 0, 0, 0);
                acc[t] = __builtin_amdgcn_mfma_f32_16x16x32_bf16(A2[t].v, B.v, acc[t], 0, 0, 0);
            }

            #pragma unroll
            for (int p = 0; p < 2; ++p) {
                f32x2 aI, aF, aG, aO;
                aI.x = acc[0][2 * p]; aI.y = acc[0][2 * p + 1];
                aF.x = acc[1][2 * p]; aF.y = acc[1][2 * p + 1];
                aG.x = acc[2][2 * p]; aG.y = acc[2][2 * p + 1];
                aO.x = acc[3][2 * p]; aO.y = acc[3][2 * p + 1];

                const f32x2 I = vexp2(aI), F = vexp2(aF);
                const f32x2 G = vexp2(aG), O = vexp2(aO);

                const f32x2 Ip = I + 1.0f, Gp = G + 1.0f;
                const f32x2 Fp = F + 1.0f, Op = O + 1.0f;

                const f32x2 R1 = vrcp(Ip * Gp);
                const f32x2 Gm = G * (2.0f * LOG2E) + (-2.0f * LOG2E);  // 2L(G-1)
                const f32x2 R2 = vrcp(Fp * Op);
                const f32x2 sf = Op * R2;
                const f32x2 so = Fp * R2;

                cs2[p] = sf * cs2[p] + Gm * R1;     // cs' = sf*cs + 2L*si*tg

                const f32x2 C2 = vexp2(cs2[p]);
                const f32x2 Rd = vrcp(C2 + 1.0f);
                const f32x2 tc = Rd * (-2.0f) + 1.0f;   // tanh(c), inf-safe
                const f32x2 hn = so * tc;

                B.u[2 * p]     = pack_hilo(hn.x);
                B.u[2 * p + 1] = pack_hilo(hn.y);
            }
        }
        xv = xnext;
    }

    // ---- MLP head: z = tanh(W1 h + b1); y = W2 z + b2. Intra-wave, no barrier.
    #pragma unroll
    for (int r = 0; r < 4; ++r) {
        const unsigned w = B.u[r];
        const float hval = __uint_as_float(w << 16) +          // hi part
                           __uint_as_float(w & 0xFFFF0000u);   // lo part
        hsm[wv][e][4 * q + r] = hval;
    }

    float hv[16];
    #pragma unroll
    for (int j = 0; j < 4; ++j) {
        const float4 t4 = *(const float4*)&hsm[wv][e][4 * j];
        hv[4 * j + 0] = t4.x; hv[4 * j + 1] = t4.y;
        hv[4 * j + 2] = t4.z; hv[4 * j + 3] = t4.w;
    }

    float z[4];
    #pragma unroll
    for (int r = 0; r < 4; ++r) {
        const int m = 4 * q + r;
        float a = b1[m];
        #pragma unroll
        for (int j = 0; j < 16; ++j) a = fmaf(W1[m * 16 + j], hv[j], a);
        const float E = fexp2(a * (2.0f * LOG2E));
        z[r] = fmaf(-2.0f, frcp(1.0f + E), 1.0f);   // safe at +-inf
    }
    #pragma unroll
    for (int r = 0; r < 4; ++r) hsm[wv][e][4 * q + r] = z[r];

    if (q < 2) {
        float a = b2[q];
        #pragma unroll
        for (int j = 0; j < 16; ++j) a = fmaf(W2[q * 16 + j], hsm[wv][e][j], a);
        out[(size_t)gelem * 2 + q] = a;
    }
}

extern "C" void kernel_launch(void* const* d_in, const int* in_sizes, int n_in,
                              void* d_out, int out_size, void* d_ws, size_t ws_size,
                              hipStream_t stream) {
    const float* x    = (const float*)d_in[0];
    const float* W_ih = (const float*)d_in[1];
    const float* W_hh = (const float*)d_in[2];
    const float* b_ih = (const float*)d_in[3];
    const float* b_hh = (const float*)d_in[4];
    const float* W1   = (const float*)d_in[5];
    const float* b1   = (const float*)d_in[6];
    const float* W2   = (const float*)d_in[7];
    const float* b2   = (const float*)d_in[8];
    float* out = (float*)d_out;

    // 32768 elems / 64 per block (4 waves x 16) = 512 blocks
    lstm_mfma_kernel<<<dim3(512), dim3(256), 0, stream>>>(
        x, W_ih, W_hh, b_ih, b_hh, W1, b1, W2, b2, out);
}

// Round 6
// 488.343 us; speedup vs baseline: 1.1058x; 1.0017x over previous
//
#include <hip/hip_runtime.h>

// LSTM B=32768, T=512, I=2, H=16 — MFMA recurrence, single-rcp gate fusion,
// asymmetric split-bf16 B packs.
// Wave = 16 elems. gates exit 2 chained MFMAs sharing one A fragment:
//   MFMA1: A1=(W_hi,W_lo) x Bh=(h_hi,h_hi) -> W_hi*h_hi + W_lo*h_hi
//   MFMA2: A1            x Bl=(h_lo,  0 ) -> W_hi*h_lo     (W_lo*h_lo dropped)
// Bh = one v_perm of h (shortest h->MFMA path); Bl built off-chain.
// Gates pre-scaled for exp2 (per-gate scale folded into W/b at setup).
// Activations per unit (7 trans, all r-chains parallel):
//   I,F,G,O = exp2(gate'); P1=(1+I)(1+G); P2=(1+F)(1+O); R=rcp(P1*P2)
//   cs' = R * fma(P1*Op, cs, (2L(G-1))*P2)   [cs = 2*log2e*c domain]
//   so  = (P1*Fp)*R;  tanh(c)=1-2*rcp(1+exp2(cs'));  h = so*tanh(c)
// r-pairs run in f32x2 -> v_pk_* on gfx950.
// C/D layout == next B layout: no LDS/cross-lane/barriers in the t-loop.

#define T_STEPS 512
#define LOG2E 1.44269504088896340736f

typedef __bf16 bf16x8 __attribute__((ext_vector_type(8)));
typedef float  f32x4  __attribute__((ext_vector_type(4)));
typedef float  f32x2  __attribute__((ext_vector_type(2)));
typedef unsigned int u32x4 __attribute__((ext_vector_type(4)));

union frag_u { u32x4 u; bf16x8 v; };

#if __has_builtin(__builtin_amdgcn_exp2f)
__device__ __forceinline__ float fexp2(float x) { return __builtin_amdgcn_exp2f(x); }
#else
__device__ __forceinline__ float fexp2(float x) { return exp2f(x); }
#endif
#if __has_builtin(__builtin_amdgcn_rcpf)
__device__ __forceinline__ float frcp(float x) { return __builtin_amdgcn_rcpf(x); }
#else
__device__ __forceinline__ float frcp(float x) { return 1.0f / x; }
#endif

__device__ __forceinline__ f32x2 vexp2(f32x2 a) { f32x2 r; r.x = fexp2(a.x); r.y = fexp2(a.y); return r; }
__device__ __forceinline__ f32x2 vrcp (f32x2 a) { f32x2 r; r.x = frcp(a.x);  r.y = frcp(a.y);  return r; }

// (hi,hi) duplicate of the bf16-truncated value: one v_perm.
__device__ __forceinline__ unsigned dup_hi(float h) {
    unsigned hb = __float_as_uint(h);
#if __has_builtin(__builtin_amdgcn_perm)
    return __builtin_amdgcn_perm(hb, hb, 0x03020302u);
#else
    return (hb >> 16) | (hb & 0xFFFF0000u);
#endif
}
// (lo, 0): residual's bf16 in low16, +0 in high16.
__device__ __forceinline__ unsigned lo_part(float h) {
    unsigned hb = __float_as_uint(h);
    float    res = h - __uint_as_float(hb & 0xFFFF0000u);
    return __float_as_uint(res) >> 16;
}
// setup-only: (hi,lo) k-interleaved pack for the A fragment
__device__ __forceinline__ unsigned pack_hilo(float h) {
    unsigned hb = __float_as_uint(h);
    float    res = h - __uint_as_float(hb & 0xFFFF0000u);
#if __has_builtin(__builtin_amdgcn_perm)
    return __builtin_amdgcn_perm(__float_as_uint(res), hb, 0x07060302u);
#else
    return (hb >> 16) | (__float_as_uint(res) & 0xFFFF0000u);
#endif
}

__global__ __launch_bounds__(256, 2)
void lstm_mfma_kernel(const float* __restrict__ x,
                      const float* __restrict__ W_ih,
                      const float* __restrict__ W_hh,
                      const float* __restrict__ b_ih,
                      const float* __restrict__ b_hh,
                      const float* __restrict__ W1,
                      const float* __restrict__ b1,
                      const float* __restrict__ W2,
                      const float* __restrict__ b2,
                      float* __restrict__ out)
{
    __shared__ float hsm[4][16][16];   // head only; per-wave private, no barriers

    const int tid  = threadIdx.x;
    const int wv   = tid >> 6;
    const int lane = tid & 63;
    const int e    = lane & 15;        // elem within wave (C/D col, B col)
    const int q    = lane >> 4;        // quad (C/D row block, B k-block)

    // per-gate exp2-argument scales, folded into all gate-row weights/biases
    const float gsc[4] = { -LOG2E, -LOG2E, 2.0f * LOG2E, -LOG2E };

    // static A fragment: s_t * W_hh gate tiles, (hi,lo) k-interleaved split-bf16.
    // A[m][k]: m = lane&15 -> gate row 16t+m; k = q*8+j -> unit 4q+(j>>1), part j&1.
    frag_u A1[4];
    #pragma unroll
    for (int t = 0; t < 4; ++t) {
        const int row = 16 * t + (lane & 15);
        const float4 w4 = *(const float4*)(W_hh + row * 16 + 4 * q);
        A1[t].u[0] = pack_hilo(w4.x * gsc[t]);
        A1[t].u[1] = pack_hilo(w4.y * gsc[t]);
        A1[t].u[2] = pack_hilo(w4.z * gsc[t]);
        A1[t].u[3] = pack_hilo(w4.w * gsc[t]);
    }

    // x-proj weights + combined bias (scaled), as f32x2 pairs over r:
    f32x2 wx2[4][2], wy2[4][2], bs2[4][2];
    #pragma unroll
    for (int t = 0; t < 4; ++t)
        #pragma unroll
        for (int p = 0; p < 2; ++p) {
            const int r0 = 16 * t + 4 * q + 2 * p;
            const int r1 = r0 + 1;
            wx2[t][p].x = W_ih[r0 * 2 + 0] * gsc[t];
            wx2[t][p].y = W_ih[r1 * 2 + 0] * gsc[t];
            wy2[t][p].x = W_ih[r0 * 2 + 1] * gsc[t];
            wy2[t][p].y = W_ih[r1 * 2 + 1] * gsc[t];
            bs2[t][p].x = (b_ih[r0] + b_hh[r0]) * gsc[t];
            bs2[t][p].y = (b_ih[r1] + b_hh[r1]) * gsc[t];
        }

    const int gelem = blockIdx.x * 64 + wv * 16 + e;
    const float4* xp = (const float4*)(x + (size_t)gelem * (T_STEPS * 2));

    frag_u Bh, Bl;                         // h_{t-1}: (hi,hi) and (lo,0) packs
    #pragma unroll
    for (int w = 0; w < 4; ++w) { Bh.u[w] = 0u; Bl.u[w] = 0u; }
    f32x2 cs2[2];                          // c in 2log2e-scaled domain, r-paired
    cs2[0] = 0.0f; cs2[1] = 0.0f;

    float4 xv = xp[0];

    for (int t2 = 0; t2 < T_STEPS / 2; ++t2) {
        const float4 xnext = xp[(t2 + 1) & (T_STEPS / 2 - 1)];

        // x-projection for BOTH halves (x-only dependent: fills wait gaps)
        f32x4 ini[2][4];
        #pragma unroll
        for (int half = 0; half < 2; ++half) {
            const float xa = half ? xv.z : xv.x;
            const float xb = half ? xv.w : xv.y;
            #pragma unroll
            for (int t = 0; t < 4; ++t)
                #pragma unroll
                for (int p = 0; p < 2; ++p) {
                    f32x2 v = wy2[t][p] * xb + bs2[t][p];   // v_pk_fma_f32
                    v = wx2[t][p] * xa + v;
                    ini[half][t][2 * p]     = v.x;
                    ini[half][t][2 * p + 1] = v.y;
                }
        }

        #pragma unroll
        for (int half = 0; half < 2; ++half) {
            f32x4 acc[4];
            #pragma unroll
            for (int t = 0; t < 4; ++t) {
                acc[t] = __builtin_amdgcn_mfma_f32_16x16x32_bf16(A1[t].v, Bh.v, ini[half][t], 0, 0, 0);
                acc[t] = __builtin_amdgcn_mfma_f32_16x16x32_bf16(A1[t].v, Bl.v, acc[t], 0, 0, 0);
            }

            #pragma unroll
            for (int p = 0; p < 2; ++p) {
                f32x2 aI, aF, aG, aO;
                aI.x = acc[0][2 * p]; aI.y = acc[0][2 * p + 1];
                aF.x = acc[1][2 * p]; aF.y = acc[1][2 * p + 1];
                aG.x = acc[2][2 * p]; aG.y = acc[2][2 * p + 1];
                aO.x = acc[3][2 * p]; aO.y = acc[3][2 * p + 1];

                const f32x2 I = vexp2(aI), F = vexp2(aF);
                const f32x2 G = vexp2(aG), O = vexp2(aO);

                const f32x2 Ip = I + 1.0f, Gp = G + 1.0f;
                const f32x2 Fp = F + 1.0f, Op = O + 1.0f;

                const f32x2 P1 = Ip * Gp;
                const f32x2 P2 = Fp * Op;
                const f32x2 R  = vrcp(P1 * P2);          // single rcp for all gates

                const f32x2 Gm   = G * (2.0f * LOG2E) + (-2.0f * LOG2E); // 2L(G-1)
                const f32x2 t_sf = P1 * Op;              // sf * (P1*P2)
                const f32x2 t_so = P1 * Fp;              // so * (P1*P2)
                const f32x2 t_ig = Gm * P2;              // 2L*si*tg * (P1*P2)

                const f32x2 u1 = t_sf * cs2[p] + t_ig;   // fma
                cs2[p] = u1 * R;                         // cs' = sf*cs + 2L*si*tg

                const f32x2 C2 = vexp2(cs2[p]);
                const f32x2 Rd = vrcp(C2 + 1.0f);
                const f32x2 tc = Rd * (-2.0f) + 1.0f;    // tanh(c), inf-safe
                const f32x2 so = t_so * R;
                const f32x2 hn = so * tc;

                Bh.u[2 * p]     = dup_hi(hn.x);          // on-chain: 1 v_perm
                Bh.u[2 * p + 1] = dup_hi(hn.y);
                Bl.u[2 * p]     = lo_part(hn.x);         // off-chain residual
                Bl.u[2 * p + 1] = lo_part(hn.y);
            }
        }
        xv = xnext;
    }

    // ---- MLP head: z = tanh(W1 h + b1); y = W2 z + b2. Intra-wave, no barrier.
    #pragma unroll
    for (int r = 0; r < 4; ++r) {
        const float hval = __uint_as_float(Bh.u[r] << 16) +   // hi part
                           __uint_as_float(Bl.u[r] << 16);    // lo part
        hsm[wv][e][4 * q + r] = hval;
    }

    float hv[16];
    #pragma unroll
    for (int j = 0; j < 4; ++j) {
        const float4 t4 = *(const float4*)&hsm[wv][e][4 * j];
        hv[4 * j + 0] = t4.x; hv[4 * j + 1] = t4.y;
        hv[4 * j + 2] = t4.z; hv[4 * j + 3] = t4.w;
    }

    float z[4];
    #pragma unroll
    for (int r = 0; r < 4; ++r) {
        const int m = 4 * q + r;
        float a = b1[m];
        #pragma unroll
        for (int j = 0; j < 16; ++j) a = fmaf(W1[m * 16 + j], hv[j], a);
        const float E = fexp2(a * (2.0f * LOG2E));
        z[r] = fmaf(-2.0f, frcp(1.0f + E), 1.0f);   // safe at +-inf
    }
    #pragma unroll
    for (int r = 0; r < 4; ++r) hsm[wv][e][4 * q + r] = z[r];

    if (q < 2) {
        float a = b2[q];
        #pragma unroll
        for (int j = 0; j < 16; ++j) a = fmaf(W2[q * 16 + j], hsm[wv][e][j], a);
        out[(size_t)gelem * 2 + q] = a;
    }
}

extern "C" void kernel_launch(void* const* d_in, const int* in_sizes, int n_in,
                              void* d_out, int out_size, void* d_ws, size_t ws_size,
                              hipStream_t stream) {
    const float* x    = (const float*)d_in[0];
    const float* W_ih = (const float*)d_in[1];
    const float* W_hh = (const float*)d_in[2];
    const float* b_ih = (const float*)d_in[3];
    const float* b_hh = (const float*)d_in[4];
    const float* W1   = (const float*)d_in[5];
    const float* b1   = (const float*)d_in[6];
    const float* W2   = (const float*)d_in[7];
    const float* b2   = (const float*)d_in[8];
    float* out = (float*)d_out;

    // 32768 elems / 64 per block (4 waves x 16) = 512 blocks
    lstm_mfma_kernel<<<dim3(512), dim3(256), 0, stream>>>(
        x, W_ih, W_hh, b_ih, b_hh, W1, b1, W2, b2, out);
}